// Round 1
// baseline (344.263 us; speedup 1.0000x reference)
//
#include <hip/hip_runtime.h>

#define B_    8
#define N_    8192
#define M_    1024
#define C1_   256
#define C2_   512
#define CIN_  768
#define CMID_ 256
#define COUT_ 256

typedef __attribute__((ext_vector_type(8))) __bf16 bf16x8;           // 4 VGPRs, MFMA A/B frag
typedef __attribute__((ext_vector_type(4))) float f32x4;             // MFMA C/D frag
typedef __attribute__((ext_vector_type(4))) unsigned short u16x4;
typedef __attribute__((ext_vector_type(8))) unsigned short u16x8;

__device__ __forceinline__ unsigned short f2bf(float f) {
  union { float f; unsigned u; } v; v.f = f;
  unsigned r = v.u + 0x7FFFu + ((v.u >> 16) & 1u);   // RNE
  return (unsigned short)(r >> 16);
}
__device__ __forceinline__ float bf2f(unsigned short h) {
  union { unsigned u; float f; } v; v.u = ((unsigned)h) << 16; return v.f;
}

// ---------------- small utility kernels ----------------

__global__ void k_zero(float* p, int n) {
  int i = blockIdx.x * 256 + threadIdx.x;
  if (i < n) p[i] = 0.f;
}

__global__ void k_cast(const float* __restrict__ in, unsigned short* __restrict__ out, int n) {
  int i = blockIdx.x * 256 + threadIdx.x;
  if (i < n) out[i] = f2bf(in[i]);
}

// known_feats (B, C2, M) f32 -> kft (B, M, C2) f32
__global__ void k_tr_kf(const float* __restrict__ in, float* __restrict__ out) {
  __shared__ float t[32][33];
  int b = blockIdx.z;
  int c0 = blockIdx.x * 32, m0 = blockIdx.y * 32;
  int tx = threadIdx.x, ty = threadIdx.y;
  const float* ip = in + ((size_t)b * C2_ + c0) * M_ + m0;
#pragma unroll
  for (int i = 0; i < 32; i += 8) t[ty + i][tx] = ip[(size_t)(ty + i) * M_ + tx];
  __syncthreads();
  float* op = out + ((size_t)b * M_ + m0) * C2_ + c0;
#pragma unroll
  for (int i = 0; i < 32; i += 8) op[(size_t)(ty + i) * C2_ + tx] = t[tx][ty + i];
}

// unknow_feats (B, C1, N) f32 -> xt[b][n][0:256] bf16 (row stride CIN_)
__global__ void k_tr_uf(const float* __restrict__ in, unsigned short* __restrict__ out) {
  __shared__ float t[32][33];
  int b = blockIdx.z;
  int c0 = blockIdx.x * 32, n0 = blockIdx.y * 32;
  int tx = threadIdx.x, ty = threadIdx.y;
  const float* ip = in + ((size_t)b * C1_ + c0) * N_ + n0;
#pragma unroll
  for (int i = 0; i < 32; i += 8) t[ty + i][tx] = ip[(size_t)(ty + i) * N_ + tx];
  __syncthreads();
  unsigned short* op = out + ((size_t)b * N_ + n0) * CIN_ + c0;
#pragma unroll
  for (int i = 0; i < 32; i += 8) op[(size_t)(ty + i) * CIN_ + tx] = f2bf(t[tx][ty + i]);
}

// ---------------- three_nn: exact fp32, matches numpy op order ----------------

__global__ void k_three_nn(const float* __restrict__ unknown, const float* __restrict__ known,
                           int* __restrict__ idx, float* __restrict__ wgt) {
  __shared__ float kx[M_], ky[M_], kz[M_];
  int b = blockIdx.x >> 5;            // 32 tiles of 256 points per batch
  int n0 = (blockIdx.x & 31) << 8;
  for (int i = threadIdx.x; i < M_; i += 256) {
    const float* kp = known + ((size_t)b * M_ + i) * 3;
    kx[i] = kp[0]; ky[i] = kp[1]; kz[i] = kp[2];
  }
  __syncthreads();
  int n = n0 + threadIdx.x;
  const float* up = unknown + ((size_t)b * N_ + n) * 3;
  float ux = up[0], uy = up[1], uz = up[2];
  float d0 = 1e30f, d1 = 1e30f, d2v = 1e30f;
  int i0 = 0, i1 = 0, i2 = 0;
  for (int j = 0; j < M_; ++j) {
    float dx = __fsub_rn(ux, kx[j]);
    float dy = __fsub_rn(uy, ky[j]);
    float dz = __fsub_rn(uz, kz[j]);
    // exact IEEE mul/add in numpy's reduction order: (dx^2 + dy^2) + dz^2
    float d = __fadd_rn(__fadd_rn(__fmul_rn(dx, dx), __fmul_rn(dy, dy)), __fmul_rn(dz, dz));
    if (d < d2v) {
      if (d < d1) {
        if (d < d0) { d2v = d1; i2 = i1; d1 = d0; i1 = i0; d0 = d; i0 = j; }
        else        { d2v = d1; i2 = i1; d1 = d;  i1 = j; }
      } else        { d2v = d;  i2 = j; }
    }
  }
  float w0 = 1.f / (d0 + 1e-8f), w1 = 1.f / (d1 + 1e-8f), w2 = 1.f / (d2v + 1e-8f);
  float s = w0 + w1 + w2;
  size_t base = ((size_t)b * N_ + n) * 3;
  idx[base] = i0; idx[base + 1] = i1; idx[base + 2] = i2;
  wgt[base] = w0 / s; wgt[base + 1] = w1 / s; wgt[base + 2] = w2 / s;
}

// interp -> xt[b][n][256:768] bf16; one block per point, coalesced row reads of kft
__global__ void k_interp(const float* __restrict__ kft, const int* __restrict__ idx,
                         const float* __restrict__ wgt, unsigned short* __restrict__ xt) {
  int bid = blockIdx.x;
  int b = bid >> 13, n = bid & (N_ - 1);
  size_t bn = (size_t)b * N_ + n;
  int i0 = idx[bn * 3], i1 = idx[bn * 3 + 1], i2 = idx[bn * 3 + 2];
  float w0 = wgt[bn * 3], w1 = wgt[bn * 3 + 1], w2 = wgt[bn * 3 + 2];
  const float* f0 = kft + ((size_t)b * M_ + i0) * C2_;
  const float* f1 = kft + ((size_t)b * M_ + i1) * C2_;
  const float* f2 = kft + ((size_t)b * M_ + i2) * C2_;
  unsigned short* o = xt + bn * CIN_ + C1_;
  for (int c = threadIdx.x; c < C2_; c += 256)
    o[c] = f2bf(w0 * f0[c] + w1 * f1[c] + w2 * f2[c]);
}

// ---------------- bf16 MFMA GEMM: C(256 x 8192) = A(256 x K) * X^T, X point-major (N x K) ----
// 128x128 tile, BK=64, 4 waves (2x2), wave tile 64x64 = 4x4 frags of 16x16x32.
// LDS tiles XOR-swizzled: byte = row*128 + (col ^ ((row&7)<<4))  (G4 recipe).
// EPI 0: out point-major bf16 (ld=256).  EPI 1: out channel-major bf16 (ld=N_).

template <int K, int EPI>
__global__ __launch_bounds__(256) void gemm_bt(const unsigned short* __restrict__ A,
                                               const unsigned short* __restrict__ Bm,
                                               unsigned short* __restrict__ C) {
  __shared__ __align__(16) char lds[32768];   // A: [0,16K), B: [16K,32K)
  const int tid = threadIdx.x;
  const int l = tid & 63;
  const int wv = tid >> 6;
  const int wr = wv >> 1, wc = wv & 1;
  const int b = blockIdx.z;
  const int o0 = blockIdx.y * 128;
  const int n0 = blockIdx.x * 128;
  const char* Ab = (const char*)A + (size_t)o0 * (K * 2);
  const char* Bb = (const char*)Bm + ((size_t)b * N_ + n0) * (K * 2);

  f32x4 zero = {0.f, 0.f, 0.f, 0.f};
  f32x4 acc[4][4];
#pragma unroll
  for (int i = 0; i < 4; ++i)
#pragma unroll
    for (int j = 0; j < 4; ++j) acc[i][j] = zero;

  // staging chunk coords: 1024 chunks of 16B per tile, 4 per thread
  int srow[4], scol[4];
#pragma unroll
  for (int i = 0; i < 4; ++i) { int q = tid + i * 256; srow[i] = q >> 3; scol[i] = (q & 7) * 16; }

  bf16x8 ra[4], rb[4];
#pragma unroll
  for (int i = 0; i < 4; ++i) {
    ra[i] = *(const bf16x8*)(Ab + (size_t)srow[i] * (K * 2) + scol[i]);
    rb[i] = *(const bf16x8*)(Bb + (size_t)srow[i] * (K * 2) + scol[i]);
  }

  const int NK = K / 64;
  for (int kt = 0; kt < NK; ++kt) {
    __syncthreads();   // previous compute done -> safe to overwrite LDS
#pragma unroll
    for (int i = 0; i < 4; ++i) {
      int d = srow[i] * 128 + (scol[i] ^ ((srow[i] & 7) << 4));
      *(bf16x8*)(lds + d) = ra[i];
      *(bf16x8*)(lds + 16384 + d) = rb[i];
    }
    __syncthreads();
    if (kt + 1 < NK) {     // prefetch next tile into regs, overlaps with MFMA below
      const char* Ak = Ab + (size_t)(kt + 1) * 128;
      const char* Bk = Bb + (size_t)(kt + 1) * 128;
#pragma unroll
      for (int i = 0; i < 4; ++i) {
        ra[i] = *(const bf16x8*)(Ak + (size_t)srow[i] * (K * 2) + scol[i]);
        rb[i] = *(const bf16x8*)(Bk + (size_t)srow[i] * (K * 2) + scol[i]);
      }
    }
#pragma unroll
    for (int kk = 0; kk < 2; ++kk) {
      bf16x8 af[4], bfr[4];
#pragma unroll
      for (int mi = 0; mi < 4; ++mi) {
        int row = wr * 64 + mi * 16 + (l & 15);
        int cb = (kk * 64 + ((l >> 4) * 16)) ^ ((row & 7) << 4);
        af[mi] = *(const bf16x8*)(lds + row * 128 + cb);
      }
#pragma unroll
      for (int ni = 0; ni < 4; ++ni) {
        int row = wc * 64 + ni * 16 + (l & 15);
        int cb = (kk * 64 + ((l >> 4) * 16)) ^ ((row & 7) << 4);
        bfr[ni] = *(const bf16x8*)(lds + 16384 + row * 128 + cb);
      }
#pragma unroll
      for (int mi = 0; mi < 4; ++mi)
#pragma unroll
        for (int ni = 0; ni < 4; ++ni)
          acc[mi][ni] = __builtin_amdgcn_mfma_f32_16x16x32_bf16(af[mi], bfr[ni], acc[mi][ni], 0, 0, 0);
    }
  }

  // epilogue: C/D frag mapping col=lane&15 (n), row=(lane>>4)*4+r (o)  [m89-verified]
#pragma unroll
  for (int mi = 0; mi < 4; ++mi) {
    int o = o0 + wr * 64 + mi * 16 + ((l >> 4) << 2);
#pragma unroll
    for (int ni = 0; ni < 4; ++ni) {
      int n = n0 + wc * 64 + ni * 16 + (l & 15);
      if (EPI == 0) {
        u16x4 pk;
#pragma unroll
        for (int r = 0; r < 4; ++r) pk[r] = f2bf(acc[mi][ni][r]);
        *(u16x4*)(C + ((size_t)b * N_ + n) * 256 + o) = pk;
      } else {
#pragma unroll
        for (int r = 0; r < 4; ++r)
          C[((size_t)b * 256 + (o + r)) * N_ + n] = f2bf(acc[mi][ni][r]);
      }
    }
  }
}

// ---------------- BN stats + apply ----------------

// y point-major (65536 rows x 256 ch): thread = channel, coalesced 512B rows
__global__ void k_stats_pm(const unsigned short* __restrict__ y, float* __restrict__ sum,
                           float* __restrict__ sq) {
  int c = threadIdx.x;
  size_t r0 = (size_t)blockIdx.x * 128;
  float s = 0.f, s2 = 0.f;
  for (int r = 0; r < 128; ++r) {
    float v = bf2f(y[(r0 + r) * 256 + c]);
    s += v; s2 = fmaf(v, v, s2);
  }
  atomicAdd(&sum[c], s); atomicAdd(&sq[c], s2);
}

// y channel-major (B*256 rows x N): block per (b,o) row
__global__ void k_stats_cm(const unsigned short* __restrict__ y, float* __restrict__ sum,
                           float* __restrict__ sq) {
  int bo = blockIdx.x;
  int o = bo & 255;
  const unsigned short* p = y + (size_t)bo * N_;
  float s = 0.f, s2 = 0.f;
  for (int i = threadIdx.x; i < N_; i += 256) { float v = bf2f(p[i]); s += v; s2 = fmaf(v, v, s2); }
#pragma unroll
  for (int off = 32; off; off >>= 1) { s += __shfl_down(s, off); s2 += __shfl_down(s2, off); }
  __shared__ float rs[4], rq[4];
  if ((threadIdx.x & 63) == 0) { rs[threadIdx.x >> 6] = s; rq[threadIdx.x >> 6] = s2; }
  __syncthreads();
  if (threadIdx.x == 0) {
    atomicAdd(&sum[o], rs[0] + rs[1] + rs[2] + rs[3]);
    atomicAdd(&sq[o],  rq[0] + rq[1] + rq[2] + rq[3]);
  }
}

__global__ void k_finalize(const float* __restrict__ sum, const float* __restrict__ sq,
                           const float* __restrict__ g, const float* __restrict__ bb,
                           float* __restrict__ scale, float* __restrict__ shift) {
  int c = threadIdx.x;
  const float inv_n = 1.f / 65536.f;
  float mean = sum[c] * inv_n;
  float var = sq[c] * inv_n - mean * mean;
  float rstd = rsqrtf(var + 1e-5f);
  float sc = g[c] * rstd;
  scale[c] = sc;
  shift[c] = bb[c] - mean * sc;
}

// in-place BN+ReLU on point-major bf16 (layer 1 -> input of gemm2)
__global__ void k_bnrelu_pm(unsigned short* __restrict__ y, const float* __restrict__ scale,
                            const float* __restrict__ shift) {
  __shared__ float sc[256], sh[256];
  sc[threadIdx.x] = scale[threadIdx.x]; sh[threadIdx.x] = shift[threadIdx.x];
  __syncthreads();
  size_t i = ((size_t)blockIdx.x * 256 + threadIdx.x) * 8;
  int c0 = (int)(i & 255);
  u16x8 v = *(const u16x8*)(y + i);
  u16x8 r;
#pragma unroll
  for (int k = 0; k < 8; ++k) {
    float f = bf2f(v[k]) * sc[c0 + k] + sh[c0 + k];
    r[k] = f2bf(fmaxf(f, 0.f));
  }
  *(u16x8*)(y + i) = r;
}

// BN+ReLU on channel-major bf16 -> fp32 d_out
__global__ void k_bnrelu_out(const unsigned short* __restrict__ y, const float* __restrict__ scale,
                             const float* __restrict__ shift, float* __restrict__ out) {
  size_t i = ((size_t)blockIdx.x * 256 + threadIdx.x) * 4;
  int c = (int)((i >> 13) & 255);
  float sc = scale[c], sh = shift[c];
  u16x4 v = *(const u16x4*)(y + i);
  f32x4 o;
#pragma unroll
  for (int k = 0; k < 4; ++k) o[k] = fmaxf(bf2f(v[k]) * sc + sh, 0.f);
  *(f32x4*)(out + i) = o;
}

// ---------------- launch ----------------

extern "C" void kernel_launch(void* const* d_in, const int* in_sizes, int n_in,
                              void* d_out, int out_size, void* d_ws, size_t ws_size,
                              hipStream_t stream) {
  const float* unknown = (const float*)d_in[0];
  const float* known   = (const float*)d_in[1];
  const float* uf      = (const float*)d_in[2];
  const float* kf      = (const float*)d_in[3];
  const float* W1      = (const float*)d_in[4];
  const float* g1      = (const float*)d_in[5];
  const float* b1      = (const float*)d_in[6];
  const float* W2      = (const float*)d_in[7];
  const float* g2      = (const float*)d_in[8];
  const float* b2      = (const float*)d_in[9];
  float* out = (float*)d_out;

  char* ws = (char*)d_ws;
  unsigned short* xt  = (unsigned short*)(ws);                    // (B,N,768) bf16   100,663,296 B
  unsigned short* y1  = (unsigned short*)(ws + 100663296);        // (B,N,256) bf16    33,554,432 B
  unsigned short* y2  = (unsigned short*)(ws + 134217728);        // (B,256,N) bf16    33,554,432 B
  float*          kft = (float*)(ws + 167772160);                 // (B,M,512) f32     16,777,216 B
  unsigned short* w1b = (unsigned short*)(ws + 184549376);        //                      393,216 B
  unsigned short* w2b = (unsigned short*)(ws + 184942592);        //                      131,072 B
  int*            idx = (int*)(ws + 185073664);                   //                      786,432 B
  float*          wgt = (float*)(ws + 185860096);                 //                      786,432 B
  float*          st  = (float*)(ws + 186646528);                 // stats block            8,192 B
  float *sum1 = st, *sq1 = st + 256, *sum2 = st + 512, *sq2 = st + 768;
  float *sc1 = st + 1024, *sh1 = st + 1280, *sc2 = st + 1536, *sh2 = st + 1792;

  k_zero<<<4, 256, 0, stream>>>(st, 1024);
  k_cast<<<768, 256, 0, stream>>>(W1, w1b, CMID_ * CIN_);
  k_cast<<<256, 256, 0, stream>>>(W2, w2b, COUT_ * CMID_);
  k_tr_kf<<<dim3(16, 32, B_), dim3(32, 8), 0, stream>>>(kf, kft);
  k_tr_uf<<<dim3(8, 256, B_), dim3(32, 8), 0, stream>>>(uf, xt);
  k_three_nn<<<B_ * 32, 256, 0, stream>>>(unknown, known, idx, wgt);
  k_interp<<<B_ * N_, 256, 0, stream>>>(kft, idx, wgt, xt);
  gemm_bt<CIN_, 0><<<dim3(64, 2, B_), 256, 0, stream>>>(w1b, xt, y1);
  k_stats_pm<<<512, 256, 0, stream>>>(y1, sum1, sq1);
  k_finalize<<<1, 256, 0, stream>>>(sum1, sq1, g1, b1, sc1, sh1);
  k_bnrelu_pm<<<8192, 256, 0, stream>>>(y1, sc1, sh1);
  gemm_bt<CMID_, 1><<<dim3(64, 2, B_), 256, 0, stream>>>(w2b, y1, y2);
  k_stats_cm<<<2048, 256, 0, stream>>>(y2, sum2, sq2);
  k_finalize<<<1, 256, 0, stream>>>(sum2, sq2, g2, b2, sc2, sh2);
  k_bnrelu_out<<<16384, 256, 0, stream>>>(y2, sc2, sh2, out);
}

// Round 2
// 230.430 us; speedup vs baseline: 1.4940x; 1.4940x over previous
//
#include <hip/hip_runtime.h>

#define B_    8
#define N_    8192
#define M_    1024
#define C1_   256
#define C2_   512
#define CIN_  768
#define CMID_ 256
#define COUT_ 256

typedef __attribute__((ext_vector_type(8))) __bf16 bf16x8;           // 4 VGPRs, MFMA A/B frag
typedef __attribute__((ext_vector_type(4))) float f32x4;             // MFMA C/D frag
typedef __attribute__((ext_vector_type(4))) unsigned short u16x4;
typedef __attribute__((ext_vector_type(8))) unsigned short u16x8;

__device__ __forceinline__ unsigned short f2bf(float f) {
  union { float f; unsigned u; } v; v.f = f;
  unsigned r = v.u + 0x7FFFu + ((v.u >> 16) & 1u);   // RNE
  return (unsigned short)(r >> 16);
}
__device__ __forceinline__ float bf2f(unsigned short h) {
  union { unsigned u; float f; } v; v.u = ((unsigned)h) << 16; return v.f;
}

// ---------------- small utility kernels ----------------

__global__ void k_zero(float* p, int n) {
  int i = blockIdx.x * 256 + threadIdx.x;
  if (i < n) p[i] = 0.f;
}

__global__ void k_cast(const float* __restrict__ in, unsigned short* __restrict__ out, int n) {
  int i = blockIdx.x * 256 + threadIdx.x;
  if (i < n) out[i] = f2bf(in[i]);
}

// known_feats (B, C2, M) f32 -> kft (B, M, C2) f32
__global__ void k_tr_kf(const float* __restrict__ in, float* __restrict__ out) {
  __shared__ float t[32][33];
  int b = blockIdx.z;
  int c0 = blockIdx.x * 32, m0 = blockIdx.y * 32;
  int tx = threadIdx.x, ty = threadIdx.y;
  const float* ip = in + ((size_t)b * C2_ + c0) * M_ + m0;
#pragma unroll
  for (int i = 0; i < 32; i += 8) t[ty + i][tx] = ip[(size_t)(ty + i) * M_ + tx];
  __syncthreads();
  float* op = out + ((size_t)b * M_ + m0) * C2_ + c0;
#pragma unroll
  for (int i = 0; i < 32; i += 8) op[(size_t)(ty + i) * C2_ + tx] = t[tx][ty + i];
}

// unknow_feats (B, C1, N) f32 -> xt[b][n][0:256] bf16 (row stride CIN_)
__global__ void k_tr_uf(const float* __restrict__ in, unsigned short* __restrict__ out) {
  __shared__ float t[32][33];
  int b = blockIdx.z;
  int c0 = blockIdx.x * 32, n0 = blockIdx.y * 32;
  int tx = threadIdx.x, ty = threadIdx.y;
  const float* ip = in + ((size_t)b * C1_ + c0) * N_ + n0;
#pragma unroll
  for (int i = 0; i < 32; i += 8) t[ty + i][tx] = ip[(size_t)(ty + i) * N_ + tx];
  __syncthreads();
  unsigned short* op = out + ((size_t)b * N_ + n0) * CIN_ + c0;
#pragma unroll
  for (int i = 0; i < 32; i += 8) op[(size_t)(ty + i) * CIN_ + tx] = f2bf(t[tx][ty + i]);
}

// ---------------- three_nn: exact fp32 (d, idx)-lex semantics, 8 lanes/query ----------------

__device__ __forceinline__ void ins3(float db, int ib, float& d0, int& i0,
                                     float& d1, int& i1, float& d2, int& i2) {
  // lexicographic (d, idx) insert — exactly reproduces jax.lax.top_k stable tie-break
  if (db < d2 || (db == d2 && ib < i2)) {
    if (db < d1 || (db == d1 && ib < i1)) {
      d2 = d1; i2 = i1;
      if (db < d0 || (db == d0 && ib < i0)) { d1 = d0; i1 = i0; d0 = db; i0 = ib; }
      else                                  { d1 = db; i1 = ib; }
    } else { d2 = db; i2 = ib; }
  }
}

__global__ __launch_bounds__(256) void k_three_nn(const float* __restrict__ unknown,
                                                  const float* __restrict__ known,
                                                  int* __restrict__ idx, float* __restrict__ wgt) {
  __shared__ __align__(16) float kpts[M_][4];   // 16 KiB, xyz + pad
  int b = blockIdx.x >> 8;                      // 256 blocks of 32 queries per batch
  int n0 = (blockIdx.x & 255) << 5;
  for (int i = threadIdx.x; i < M_; i += 256) {
    const float* kp = known + ((size_t)b * M_ + i) * 3;
    kpts[i][0] = kp[0]; kpts[i][1] = kp[1]; kpts[i][2] = kp[2];
  }
  __syncthreads();
  const int l = threadIdx.x & 63;
  const int j = l & 7;                          // chunk within query: scans i = 8t + j
  const int q = ((threadIdx.x >> 6) << 3) + (l >> 3);   // query 0..31 within block
  const int n = n0 + q;
  const float* up = unknown + ((size_t)b * N_ + n) * 3;
  float ux = up[0], uy = up[1], uz = up[2];
  float d0 = 1e30f, d1 = 1e30f, d2v = 1e30f;
  int i0 = 0, i1 = 0, i2 = 0;
  for (int t = 0; t < 128; ++t) {
    int i = t * 8 + j;
    f32x4 p = *(const f32x4*)kpts[i];           // conflict-free broadcast (8 consecutive 16B)
    float dx = __fsub_rn(ux, p[0]);
    float dy = __fsub_rn(uy, p[1]);
    float dz = __fsub_rn(uz, p[2]);
    float d = __fadd_rn(__fadd_rn(__fmul_rn(dx, dx), __fmul_rn(dy, dy)), __fmul_rn(dz, dz));
    if (d < d2v) {        // within-lane idx increasing -> strict < is (d,idx)-lex
      if (d < d1) {
        if (d < d0) { d2v = d1; i2 = i1; d1 = d0; i1 = i0; d0 = d; i0 = i; }
        else        { d2v = d1; i2 = i1; d1 = d;  i1 = i; }
      } else        { d2v = d;  i2 = i; }
    }
  }
  // butterfly merge across the 8 chunk-lanes
#pragma unroll
  for (int m = 1; m <= 4; m <<= 1) {
    float e0 = __shfl_xor(d0, m), e1 = __shfl_xor(d1, m), e2 = __shfl_xor(d2v, m);
    int   f0 = __shfl_xor(i0, m), f1 = __shfl_xor(i1, m), f2 = __shfl_xor(i2, m);
    ins3(e0, f0, d0, i0, d1, i1, d2v, i2);
    ins3(e1, f1, d0, i0, d1, i1, d2v, i2);
    ins3(e2, f2, d0, i0, d1, i1, d2v, i2);
  }
  if (j == 0) {
    float w0 = 1.f / (d0 + 1e-8f), w1 = 1.f / (d1 + 1e-8f), w2 = 1.f / (d2v + 1e-8f);
    float s = w0 + w1 + w2;
    size_t base = ((size_t)b * N_ + n) * 3;
    idx[base] = i0; idx[base + 1] = i1; idx[base + 2] = i2;
    wgt[base] = w0 / s; wgt[base + 1] = w1 / s; wgt[base + 2] = w2 / s;
  }
}

// interp -> xt[b][n][256:768] bf16; 8 points/block, 32 lanes each, float4 gathers
__global__ __launch_bounds__(256) void k_interp(const float* __restrict__ kft, const int* __restrict__ idx,
                                                const float* __restrict__ wgt, unsigned short* __restrict__ xt) {
  int pb = blockIdx.x * 8 + (threadIdx.x >> 5);   // global point = b*N + n
  int lane = threadIdx.x & 31;
  int b = pb >> 13;
  size_t t3 = (size_t)pb * 3;
  int i0 = idx[t3], i1 = idx[t3 + 1], i2 = idx[t3 + 2];
  float w0 = wgt[t3], w1 = wgt[t3 + 1], w2 = wgt[t3 + 2];
  const f32x4* f0 = (const f32x4*)(kft + ((size_t)b * M_ + i0) * C2_);
  const f32x4* f1 = (const f32x4*)(kft + ((size_t)b * M_ + i1) * C2_);
  const f32x4* f2 = (const f32x4*)(kft + ((size_t)b * M_ + i2) * C2_);
  unsigned short* o = xt + (size_t)pb * CIN_ + C1_;
#pragma unroll
  for (int k = 0; k < 4; ++k) {
    int c4 = lane + 32 * k;
    f32x4 a = f0[c4], bb = f1[c4], cc = f2[c4];
    u16x4 r;
#pragma unroll
    for (int e = 0; e < 4; ++e) r[e] = f2bf(w0 * a[e] + w1 * bb[e] + w2 * cc[e]);
    *(u16x4*)(o + 4 * c4) = r;
  }
}

// ---------------- bf16 MFMA GEMM: C(256 x 8192) = A(256 x K) * X^T, X point-major (N x K) ----
// 128x128 tile, BK=64, 4 waves (2x2), wave tile 64x64 = 4x4 frags of 16x16x32.
// LDS tiles XOR-swizzled: byte = row*128 + (col ^ ((row&7)<<4))  (G4 recipe).
// EPI 0: out point-major bf16 (ld=256).  EPI 1: out channel-major bf16 (ld=N_).

template <int K, int EPI>
__global__ __launch_bounds__(256) void gemm_bt(const unsigned short* __restrict__ A,
                                               const unsigned short* __restrict__ Bm,
                                               unsigned short* __restrict__ C) {
  __shared__ __align__(16) char lds[32768];   // A: [0,16K), B: [16K,32K)
  const int tid = threadIdx.x;
  const int l = tid & 63;
  const int wv = tid >> 6;
  const int wr = wv >> 1, wc = wv & 1;
  const int b = blockIdx.z;
  const int o0 = blockIdx.y * 128;
  const int n0 = blockIdx.x * 128;
  const char* Ab = (const char*)A + (size_t)o0 * (K * 2);
  const char* Bb = (const char*)Bm + ((size_t)b * N_ + n0) * (K * 2);

  f32x4 zero = {0.f, 0.f, 0.f, 0.f};
  f32x4 acc[4][4];
#pragma unroll
  for (int i = 0; i < 4; ++i)
#pragma unroll
    for (int j = 0; j < 4; ++j) acc[i][j] = zero;

  // staging chunk coords: 1024 chunks of 16B per tile, 4 per thread
  int srow[4], scol[4];
#pragma unroll
  for (int i = 0; i < 4; ++i) { int q = tid + i * 256; srow[i] = q >> 3; scol[i] = (q & 7) * 16; }

  bf16x8 ra[4], rb[4];
#pragma unroll
  for (int i = 0; i < 4; ++i) {
    ra[i] = *(const bf16x8*)(Ab + (size_t)srow[i] * (K * 2) + scol[i]);
    rb[i] = *(const bf16x8*)(Bb + (size_t)srow[i] * (K * 2) + scol[i]);
  }

  const int NK = K / 64;
  for (int kt = 0; kt < NK; ++kt) {
    __syncthreads();   // previous compute done -> safe to overwrite LDS
#pragma unroll
    for (int i = 0; i < 4; ++i) {
      int d = srow[i] * 128 + (scol[i] ^ ((srow[i] & 7) << 4));
      *(bf16x8*)(lds + d) = ra[i];
      *(bf16x8*)(lds + 16384 + d) = rb[i];
    }
    __syncthreads();
    if (kt + 1 < NK) {     // prefetch next tile into regs, overlaps with MFMA below
      const char* Ak = Ab + (size_t)(kt + 1) * 128;
      const char* Bk = Bb + (size_t)(kt + 1) * 128;
#pragma unroll
      for (int i = 0; i < 4; ++i) {
        ra[i] = *(const bf16x8*)(Ak + (size_t)srow[i] * (K * 2) + scol[i]);
        rb[i] = *(const bf16x8*)(Bk + (size_t)srow[i] * (K * 2) + scol[i]);
      }
    }
#pragma unroll
    for (int kk = 0; kk < 2; ++kk) {
      bf16x8 af[4], bfr[4];
#pragma unroll
      for (int mi = 0; mi < 4; ++mi) {
        int row = wr * 64 + mi * 16 + (l & 15);
        int cb = (kk * 64 + ((l >> 4) * 16)) ^ ((row & 7) << 4);
        af[mi] = *(const bf16x8*)(lds + row * 128 + cb);
      }
#pragma unroll
      for (int ni = 0; ni < 4; ++ni) {
        int row = wc * 64 + ni * 16 + (l & 15);
        int cb = (kk * 64 + ((l >> 4) * 16)) ^ ((row & 7) << 4);
        bfr[ni] = *(const bf16x8*)(lds + 16384 + row * 128 + cb);
      }
#pragma unroll
      for (int mi = 0; mi < 4; ++mi)
#pragma unroll
        for (int ni = 0; ni < 4; ++ni)
          acc[mi][ni] = __builtin_amdgcn_mfma_f32_16x16x32_bf16(af[mi], bfr[ni], acc[mi][ni], 0, 0, 0);
    }
  }

  // epilogue: C/D frag mapping col=lane&15 (n), row=(lane>>4)*4+r (o)  [m89-verified]
#pragma unroll
  for (int mi = 0; mi < 4; ++mi) {
    int o = o0 + wr * 64 + mi * 16 + ((l >> 4) << 2);
#pragma unroll
    for (int ni = 0; ni < 4; ++ni) {
      int n = n0 + wc * 64 + ni * 16 + (l & 15);
      if (EPI == 0) {
        u16x4 pk;
#pragma unroll
        for (int r = 0; r < 4; ++r) pk[r] = f2bf(acc[mi][ni][r]);
        *(u16x4*)(C + ((size_t)b * N_ + n) * 256 + o) = pk;
      } else {
#pragma unroll
        for (int r = 0; r < 4; ++r)
          C[((size_t)b * 256 + (o + r)) * N_ + n] = f2bf(acc[mi][ni][r]);
      }
    }
  }
}

// ---------------- BN stats + apply ----------------

// y point-major (65536 rows x 256 ch): thread = channel, coalesced 512B rows
__global__ void k_stats_pm(const unsigned short* __restrict__ y, float* __restrict__ sum,
                           float* __restrict__ sq) {
  int c = threadIdx.x;
  size_t r0 = (size_t)blockIdx.x * 128;
  float s = 0.f, s2 = 0.f;
  for (int r = 0; r < 128; ++r) {
    float v = bf2f(y[(r0 + r) * 256 + c]);
    s += v; s2 = fmaf(v, v, s2);
  }
  atomicAdd(&sum[c], s); atomicAdd(&sq[c], s2);
}

// y channel-major (B*256 rows x N): block per (b,o) row
__global__ void k_stats_cm(const unsigned short* __restrict__ y, float* __restrict__ sum,
                           float* __restrict__ sq) {
  int bo = blockIdx.x;
  int o = bo & 255;
  const unsigned short* p = y + (size_t)bo * N_;
  float s = 0.f, s2 = 0.f;
  for (int i = threadIdx.x; i < N_; i += 256) { float v = bf2f(p[i]); s += v; s2 = fmaf(v, v, s2); }
#pragma unroll
  for (int off = 32; off; off >>= 1) { s += __shfl_down(s, off); s2 += __shfl_down(s2, off); }
  __shared__ float rs[4], rq[4];
  if ((threadIdx.x & 63) == 0) { rs[threadIdx.x >> 6] = s; rq[threadIdx.x >> 6] = s2; }
  __syncthreads();
  if (threadIdx.x == 0) {
    atomicAdd(&sum[o], rs[0] + rs[1] + rs[2] + rs[3]);
    atomicAdd(&sq[o],  rq[0] + rq[1] + rq[2] + rq[3]);
  }
}

__global__ void k_finalize(const float* __restrict__ sum, const float* __restrict__ sq,
                           const float* __restrict__ g, const float* __restrict__ bb,
                           float* __restrict__ scale, float* __restrict__ shift) {
  int c = threadIdx.x;
  const float inv_n = 1.f / 65536.f;
  float mean = sum[c] * inv_n;
  float var = sq[c] * inv_n - mean * mean;
  float rstd = rsqrtf(var + 1e-5f);
  float sc = g[c] * rstd;
  scale[c] = sc;
  shift[c] = bb[c] - mean * sc;
}

// in-place BN+ReLU on point-major bf16 (layer 1 -> input of gemm2)
__global__ void k_bnrelu_pm(unsigned short* __restrict__ y, const float* __restrict__ scale,
                            const float* __restrict__ shift) {
  __shared__ float sc[256], sh[256];
  sc[threadIdx.x] = scale[threadIdx.x]; sh[threadIdx.x] = shift[threadIdx.x];
  __syncthreads();
  size_t i = ((size_t)blockIdx.x * 256 + threadIdx.x) * 8;
  int c0 = (int)(i & 255);
  u16x8 v = *(const u16x8*)(y + i);
  u16x8 r;
#pragma unroll
  for (int k = 0; k < 8; ++k) {
    float f = bf2f(v[k]) * sc[c0 + k] + sh[c0 + k];
    r[k] = f2bf(fmaxf(f, 0.f));
  }
  *(u16x8*)(y + i) = r;
}

// BN+ReLU on channel-major bf16 -> fp32 d_out
__global__ void k_bnrelu_out(const unsigned short* __restrict__ y, const float* __restrict__ scale,
                             const float* __restrict__ shift, float* __restrict__ out) {
  size_t i = ((size_t)blockIdx.x * 256 + threadIdx.x) * 4;
  int c = (int)((i >> 13) & 255);
  float sc = scale[c], sh = shift[c];
  u16x4 v = *(const u16x4*)(y + i);
  f32x4 o;
#pragma unroll
  for (int k = 0; k < 4; ++k) o[k] = fmaxf(bf2f(v[k]) * sc + sh, 0.f);
  *(f32x4*)(out + i) = o;
}

// ---------------- launch ----------------

extern "C" void kernel_launch(void* const* d_in, const int* in_sizes, int n_in,
                              void* d_out, int out_size, void* d_ws, size_t ws_size,
                              hipStream_t stream) {
  const float* unknown = (const float*)d_in[0];
  const float* known   = (const float*)d_in[1];
  const float* uf      = (const float*)d_in[2];
  const float* kf      = (const float*)d_in[3];
  const float* W1      = (const float*)d_in[4];
  const float* g1      = (const float*)d_in[5];
  const float* b1      = (const float*)d_in[6];
  const float* W2      = (const float*)d_in[7];
  const float* g2      = (const float*)d_in[8];
  const float* b2      = (const float*)d_in[9];
  float* out = (float*)d_out;

  char* ws = (char*)d_ws;
  unsigned short* xt  = (unsigned short*)(ws);                    // (B,N,768) bf16   100,663,296 B
  unsigned short* y1  = (unsigned short*)(ws + 100663296);        // (B,N,256) bf16    33,554,432 B
  unsigned short* y2  = (unsigned short*)(ws + 134217728);        // (B,256,N) bf16    33,554,432 B
  float*          kft = (float*)(ws + 167772160);                 // (B,M,512) f32     16,777,216 B
  unsigned short* w1b = (unsigned short*)(ws + 184549376);        //                      393,216 B
  unsigned short* w2b = (unsigned short*)(ws + 184942592);        //                      131,072 B
  int*            idx = (int*)(ws + 185073664);                   //                      786,432 B
  float*          wgt = (float*)(ws + 185860096);                 //                      786,432 B
  float*          st  = (float*)(ws + 186646528);                 // stats block            8,192 B
  float *sum1 = st, *sq1 = st + 256, *sum2 = st + 512, *sq2 = st + 768;
  float *sc1 = st + 1024, *sh1 = st + 1280, *sc2 = st + 1536, *sh2 = st + 1792;

  k_zero<<<4, 256, 0, stream>>>(st, 1024);
  k_cast<<<768, 256, 0, stream>>>(W1, w1b, CMID_ * CIN_);
  k_cast<<<256, 256, 0, stream>>>(W2, w2b, COUT_ * CMID_);
  k_tr_kf<<<dim3(16, 32, B_), dim3(32, 8), 0, stream>>>(kf, kft);
  k_tr_uf<<<dim3(8, 256, B_), dim3(32, 8), 0, stream>>>(uf, xt);
  k_three_nn<<<B_ * 256, 256, 0, stream>>>(unknown, known, idx, wgt);
  k_interp<<<B_ * N_ / 8, 256, 0, stream>>>(kft, idx, wgt, xt);
  gemm_bt<CIN_, 0><<<dim3(64, 2, B_), 256, 0, stream>>>(w1b, xt, y1);
  k_stats_pm<<<512, 256, 0, stream>>>(y1, sum1, sq1);
  k_finalize<<<1, 256, 0, stream>>>(sum1, sq1, g1, b1, sc1, sh1);
  k_bnrelu_pm<<<8192, 256, 0, stream>>>(y1, sc1, sh1);
  gemm_bt<CMID_, 1><<<dim3(64, 2, B_), 256, 0, stream>>>(w2b, y1, y2);
  k_stats_cm<<<2048, 256, 0, stream>>>(y2, sum2, sq2);
  k_finalize<<<1, 256, 0, stream>>>(sum2, sq2, g2, b2, sc2, sh2);
  k_bnrelu_out<<<16384, 256, 0, stream>>>(y2, sc2, sh2, out);
}